// Round 1
// baseline (12845.470 us; speedup 1.0000x reference)
//
#include <hip/hip_runtime.h>
#include <hip/hip_bf16.h>

typedef _Float16 f16;
typedef _Float16 f16x8 __attribute__((ext_vector_type(8)));
typedef _Float16 f16x4 __attribute__((ext_vector_type(4)));
typedef float    f32x4 __attribute__((ext_vector_type(4)));
typedef float    f32x2 __attribute__((ext_vector_type(2)));
typedef unsigned long long u64;

#define DEV static __device__ __forceinline__

// XOR swizzle for [rows][32 f16] (64B-row) LDS tiles: conflict-free b128 frag reads.
DEV int swz(int o) { return o ^ (((o >> 6) & 7) << 4); }

DEV f16x8 u2h8(u64 lo, u64 hi) { union { u64 a[2]; f16x8 b; } c; c.a[0] = lo; c.a[1] = hi; return c.b; }
DEV f16x4 u2h4(u64 v) { union { u64 a; f16x4 b; } c; c.a = v; return c.b; }
DEV float sigmf(float x) { return 1.0f / (1.0f + __expf(-x)); }
DEV float tanhf_(float x) { float e = __expf(2.0f * x); return 1.0f - 2.0f / (e + 1.0f); }

// ---------------------------------------------------------------- embed gather
__global__ __launch_bounds__(256) void k_embed(const int* __restrict__ x,
                                               const float* __restrict__ ew,
                                               f16* __restrict__ out) {
  int i = (blockIdx.x * 256 + threadIdx.x) * 4;     // element index into [32768][512]
  int tok = x[i >> 9];
  f32x4 v = *(const f32x4*)(ew + (tok << 9) + (i & 511));
  f16x4 h; h[0] = (f16)v[0]; h[1] = (f16)v[1]; h[2] = (f16)v[2]; h[3] = (f16)v[3];
  *(f16x4*)(out + i) = h;
}

// ------------------------------------------------- conv1d(k=3,SAME)+BN+ReLU
// Implicit GEMM: M=32768 (tiles of 128 rows, batch-aligned), N=512, K=3*512.
__global__ __launch_bounds__(256, 2) void k_conv(
    const f16* __restrict__ in, const float* __restrict__ w,
    const float* __restrict__ bias, const float* __restrict__ bnsc,
    const float* __restrict__ bnof, const float* __restrict__ bnmu,
    const float* __restrict__ bnva, f16* __restrict__ outp,
    const f16* __restrict__ zp) {
  __shared__ f16 Al[4096];   // A tile [128][32] f16, swizzled
  __shared__ f16 Bl[4096];   // B tile transposed [128 cols][32 k] f16, swizzled
  int tid = threadIdx.x, lane = tid & 63, wv = tid >> 6;
  int mb = blockIdx.x, nb = blockIdx.y;
  int wm = (wv >> 1) * 64, wn = (wv & 1) * 64;
  int bb = mb >> 3, l0 = (mb & 7) << 7;      // batch, seq base of tile
  int ar = tid >> 1, ah = tid & 1;           // A staging: row, 32B half
  int bc = (tid & 63) * 2, bkg = tid >> 6;   // B staging: col pair, k-group
  int ko = (lane >> 4) << 4;                 // fragment k byte offset
  f32x4 acc[4][4] = {};
  for (int tap = 0; tap < 3; ++tap) {
    const float* wt = w + tap * 512 * 512 + nb * 128;
    int sl = l0 + ar + tap - 1;              // source seq pos (halo)
    const f16* abase = (sl >= 0 && sl < 1024) ? in + ((bb << 10) + sl) * 512 : nullptr;
    for (int kk = 0; kk < 16; ++kk) {
      const f16* ap = abase ? (abase + kk * 32 + ah * 16) : zp;
      f16x8 a0 = *(const f16x8*)(ap);
      f16x8 a1 = *(const f16x8*)(ap + 8);
      int ao = ar * 64 + ah * 32;
      *(f16x8*)((char*)Al + swz(ao))      = a0;
      *(f16x8*)((char*)Al + swz(ao + 16)) = a1;
      f16x8 b0, b1;
      #pragma unroll
      for (int j = 0; j < 8; ++j) {
        f32x2 f = *(const f32x2*)(wt + (size_t)(kk * 32 + bkg * 8 + j) * 512 + bc);
        b0[j] = (f16)f[0]; b1[j] = (f16)f[1];
      }
      *(f16x8*)((char*)Bl + swz(bc * 64 + bkg * 16))       = b0;
      *(f16x8*)((char*)Bl + swz((bc + 1) * 64 + bkg * 16)) = b1;
      __syncthreads();
      f16x8 af[4], bf[4];
      #pragma unroll
      for (int m = 0; m < 4; ++m)
        af[m] = *(const f16x8*)((char*)Al + swz((wm + m * 16 + (lane & 15)) * 64 + ko));
      #pragma unroll
      for (int n = 0; n < 4; ++n)
        bf[n] = *(const f16x8*)((char*)Bl + swz((wn + n * 16 + (lane & 15)) * 64 + ko));
      #pragma unroll
      for (int m = 0; m < 4; ++m)
        #pragma unroll
        for (int n = 0; n < 4; ++n)
          acc[m][n] = __builtin_amdgcn_mfma_f32_16x16x32_f16(af[m], bf[n], acc[m][n], 0, 0, 0);
      __syncthreads();
    }
  }
  #pragma unroll
  for (int n = 0; n < 4; ++n) {
    int col = nb * 128 + wn + n * 16 + (lane & 15);
    float aa = bnsc[col] / sqrtf(bnva[col] + 1e-5f);
    float bbv = (bias[col] - bnmu[col]) * aa + bnof[col];
    #pragma unroll
    for (int m = 0; m < 4; ++m)
      #pragma unroll
      for (int r = 0; r < 4; ++r) {
        int row = mb * 128 + wm + m * 16 + ((lane >> 4) << 2) + r;
        float v = acc[m][n][r] * aa + bbv;
        outp[(size_t)row * 512 + col] = (f16)fmaxf(v, 0.0f);
      }
  }
}

// --------------------------------- Gx = x @ W[:512] + b  (per direction, fp16 out)
__global__ __launch_bounds__(256, 2) void k_gx(
    const f16* __restrict__ in, const float* __restrict__ W,
    const float* __restrict__ bias, f16* __restrict__ gx) {
  __shared__ f16 Al[4096];
  __shared__ f16 Bl[4096];
  int tid = threadIdx.x, lane = tid & 63, wv = tid >> 6;
  int mb = blockIdx.x, nb = blockIdx.y;   // nb 0..15 (N=2048)
  int wm = (wv >> 1) * 64, wn = (wv & 1) * 64;
  int ar = tid >> 1, ah = tid & 1;
  int bc = (tid & 63) * 2, bkg = tid >> 6;
  int ko = (lane >> 4) << 4;
  f32x4 acc[4][4] = {};
  for (int kk = 0; kk < 16; ++kk) {
    const f16* ap = in + (size_t)(mb * 128 + ar) * 512 + kk * 32 + ah * 16;
    f16x8 a0 = *(const f16x8*)(ap);
    f16x8 a1 = *(const f16x8*)(ap + 8);
    int ao = ar * 64 + ah * 32;
    *(f16x8*)((char*)Al + swz(ao))      = a0;
    *(f16x8*)((char*)Al + swz(ao + 16)) = a1;
    f16x8 b0, b1;
    #pragma unroll
    for (int j = 0; j < 8; ++j) {
      f32x2 f = *(const f32x2*)(W + (size_t)(kk * 32 + bkg * 8 + j) * 2048 + nb * 128 + bc);
      b0[j] = (f16)f[0]; b1[j] = (f16)f[1];
    }
    *(f16x8*)((char*)Bl + swz(bc * 64 + bkg * 16))       = b0;
    *(f16x8*)((char*)Bl + swz((bc + 1) * 64 + bkg * 16)) = b1;
    __syncthreads();
    f16x8 af[4], bf[4];
    #pragma unroll
    for (int m = 0; m < 4; ++m)
      af[m] = *(const f16x8*)((char*)Al + swz((wm + m * 16 + (lane & 15)) * 64 + ko));
    #pragma unroll
    for (int n = 0; n < 4; ++n)
      bf[n] = *(const f16x8*)((char*)Bl + swz((wn + n * 16 + (lane & 15)) * 64 + ko));
    #pragma unroll
    for (int m = 0; m < 4; ++m)
      #pragma unroll
      for (int n = 0; n < 4; ++n)
        acc[m][n] = __builtin_amdgcn_mfma_f32_16x16x32_f16(af[m], bf[n], acc[m][n], 0, 0, 0);
    __syncthreads();
  }
  #pragma unroll
  for (int n = 0; n < 4; ++n) {
    int col = nb * 128 + wn + n * 16 + (lane & 15);
    float bv = bias[col];
    #pragma unroll
    for (int m = 0; m < 4; ++m)
      #pragma unroll
      for (int r = 0; r < 4; ++r) {
        int row = mb * 128 + wm + m * 16 + ((lane >> 4) << 2) + r;
        gx[(size_t)row * 2048 + col] = (f16)(acc[m][n][r] + bv);
      }
  }
}

// ------------------------------------------------------------- BiLSTM recurrence
// 32 persistent WGs: dir = blk>>4, each WG owns 32 hidden units (128 gate cols).
// W_h slice lives in VGPRs as MFMA B-fragments. Flag-based producer/consumer sync.
__global__ __launch_bounds__(256, 1) void k_lstm(
    const f16* __restrict__ gx0, const f16* __restrict__ gx1,
    const float* __restrict__ Wf, const float* __restrict__ Wb,
    const int* __restrict__ lens,
    f16* __restrict__ hb, unsigned* __restrict__ flg,
    float* __restrict__ outp) {
  __shared__ float gl[32 * 129];  // gates exchange [batch][4*32 cols], stride 129
  int wgid = blockIdx.x; int dir = wgid >> 4; int wg = wgid & 15;
  int tid = threadIdx.x, lane = tid & 63, wv = tid >> 6;  // wv = gate (i,g,f,o)
  const float* W = dir ? Wb : Wf;
  const f16* gx = dir ? gx1 : gx0;
  f16* h0 = hb + dir * 32768;                       // 2 buffers of [32][512] f16
  unsigned* myflag = flg + (dir * 16 + wg) * 16;    // 64B-strided flags
  const unsigned* pollp = flg + dir * 256 + (lane & 15) * 16;

  // Preload W_h B-fragments: bfr[nt][kk] covers cols wv*512+wg*32+nt*16+(lane&15),
  // rows 512 + kk*32 + (lane>>4)*8 + j.
  f16x8 bfr[2][16];
  {
    int cc0 = wv * 512 + wg * 32 + (lane & 15);
    int r0 = 512 + ((lane >> 4) << 3);
    #pragma unroll
    for (int nt = 0; nt < 2; ++nt)
      #pragma unroll
      for (int kk = 0; kk < 16; ++kk) {
        f16x8 t;
        #pragma unroll
        for (int j = 0; j < 8; ++j)
          t[j] = (f16)W[(size_t)(r0 + kk * 32 + j) * 2048 + cc0 + nt * 16];
        bfr[nt][kk] = t;
      }
  }
  int cb = tid >> 3, u4 = (tid & 7) << 2;   // cell phase: batch, unit base
  int lenc = lens[cb];
  int lenr0 = lens[lane & 15];
  int lenr1 = lens[16 + (lane & 15)];
  int kbyte = ((lane >> 4) << 4);
  float c4[4] = {0.f, 0.f, 0.f, 0.f};

  for (int s = 0; s < 1024; ++s) {
    int l = dir ? (1023 - s) : s;
    // Prefetch this step's Gx (independent of h) before polling.
    const f16* gp = gx + ((size_t)((cb << 10) + l)) * 2048 + wg * 32 + u4;
    u64 gi_ = *(const u64*)(gp);
    u64 gg_ = *(const u64*)(gp + 512);
    u64 gf_ = *(const u64*)(gp + 1024);
    u64 go_ = *(const u64*)(gp + 1536);
    // Wait for all 16 WGs of this direction to have published h_s. (bounded spin)
    for (int spin = 0; spin < (1 << 22); ++spin) {
      unsigned v = __hip_atomic_load(pollp, __ATOMIC_RELAXED, __HIP_MEMORY_SCOPE_AGENT);
      if (__all((int)(v >= (unsigned)s))) break;
      __builtin_amdgcn_s_sleep(2);
    }
    __builtin_amdgcn_fence(__ATOMIC_ACQUIRE, "agent");

    const char* hc = (const char*)(h0 + ((s & 1) << 14));
    bool rst0 = dir && (l >= lenr0 - 1);
    bool rst1 = dir && (l >= lenr1 - 1);
    int rb0 = (lane & 15) * 1024 + kbyte;
    int rb1 = rb0 + 16 * 1024;
    f32x4 a00 = {0,0,0,0}, a01 = {0,0,0,0}, a10 = {0,0,0,0}, a11 = {0,0,0,0};
    #pragma unroll
    for (int kk = 0; kk < 16; ++kk) {
      u64 x0 = __hip_atomic_load((const u64*)(hc + rb0 + kk * 64),     __ATOMIC_RELAXED, __HIP_MEMORY_SCOPE_AGENT);
      u64 x1 = __hip_atomic_load((const u64*)(hc + rb0 + kk * 64 + 8), __ATOMIC_RELAXED, __HIP_MEMORY_SCOPE_AGENT);
      u64 y0 = __hip_atomic_load((const u64*)(hc + rb1 + kk * 64),     __ATOMIC_RELAXED, __HIP_MEMORY_SCOPE_AGENT);
      u64 y1 = __hip_atomic_load((const u64*)(hc + rb1 + kk * 64 + 8), __ATOMIC_RELAXED, __HIP_MEMORY_SCOPE_AGENT);
      if (rst0) { x0 = 0; x1 = 0; }
      if (rst1) { y0 = 0; y1 = 0; }
      f16x8 a0 = u2h8(x0, x1), a1 = u2h8(y0, y1);
      a00 = __builtin_amdgcn_mfma_f32_16x16x32_f16(a0, bfr[0][kk], a00, 0, 0, 0);
      a01 = __builtin_amdgcn_mfma_f32_16x16x32_f16(a0, bfr[1][kk], a01, 0, 0, 0);
      a10 = __builtin_amdgcn_mfma_f32_16x16x32_f16(a1, bfr[0][kk], a10, 0, 0, 0);
      a11 = __builtin_amdgcn_mfma_f32_16x16x32_f16(a1, bfr[1][kk], a11, 0, 0, 0);
    }
    int colb = wv * 32 + (lane & 15);
    int rowb = ((lane >> 4) << 2);
    #pragma unroll
    for (int r = 0; r < 4; ++r) {
      gl[(rowb + r) * 129 + colb]           = a00[r];
      gl[(rowb + r) * 129 + colb + 16]      = a01[r];
      gl[(rowb + r + 16) * 129 + colb]      = a10[r];
      gl[(rowb + r + 16) * 129 + colb + 16] = a11[r];
    }
    __syncthreads();
    f16x4 gi4 = u2h4(gi_), gg4 = u2h4(gg_), gf4 = u2h4(gf_), go4 = u2h4(go_);
    bool rstc = dir && (l >= lenc - 1);
    float hv[4];
    #pragma unroll
    for (int q = 0; q < 4; ++q) {
      int u = u4 + q;
      float gi = gl[cb * 129 + u]      + (float)gi4[q];
      float gg = gl[cb * 129 + 32 + u] + (float)gg4[q];
      float gf = gl[cb * 129 + 64 + u] + (float)gf4[q];
      float go = gl[cb * 129 + 96 + u] + (float)go4[q];
      float cp = rstc ? 0.f : c4[q];
      float it = sigmf(gi);
      float gt = tanhf_(gg);
      float ft = sigmf(gf + 1.0f);
      float ot = sigmf(go);
      float cn = ft * cp + it * gt;
      c4[q] = cn;
      hv[q] = ot * tanhf_(cn);
    }
    union { f16x4 h; u64 u; } hp;
    #pragma unroll
    for (int q = 0; q < 4; ++q) hp.h[q] = (f16)hv[q];
    f16* hdst = h0 + (((s + 1) & 1) << 14) + (cb << 9) + wg * 32 + u4;
    __hip_atomic_store((u64*)hdst, hp.u, __ATOMIC_RELAXED, __HIP_MEMORY_SCOPE_AGENT);
    union { f32x2 f; u64 u; } o0, o1;
    o0.f[0] = hv[0]; o0.f[1] = hv[1]; o1.f[0] = hv[2]; o1.f[1] = hv[3];
    float* od = outp + ((size_t)((cb << 10) + l) << 10) + (dir << 9) + wg * 32 + u4;
    __hip_atomic_store((u64*)od,       o0.u, __ATOMIC_RELAXED, __HIP_MEMORY_SCOPE_AGENT);
    __hip_atomic_store((u64*)(od + 2), o1.u, __ATOMIC_RELAXED, __HIP_MEMORY_SCOPE_AGENT);
    __threadfence();
    __syncthreads();
    if (tid == 0)
      __hip_atomic_store(myflag, (unsigned)(s + 1), __ATOMIC_RELEASE, __HIP_MEMORY_SCOPE_AGENT);
  }
}

// ---------------------------------------------------------------------- launch
extern "C" void kernel_launch(void* const* d_in, const int* in_sizes, int n_in,
                              void* d_out, int out_size, void* d_ws, size_t ws_size,
                              hipStream_t stream) {
  const int*   x    = (const int*)d_in[0];
  const int*   len  = (const int*)d_in[1];
  const float* ew   = (const float*)d_in[2];
  const float* w1   = (const float*)d_in[3];
  const float* cb1  = (const float*)d_in[4];
  const float* w2   = (const float*)d_in[5];
  const float* cb2  = (const float*)d_in[6];
  const float* w3   = (const float*)d_in[7];
  const float* cb3  = (const float*)d_in[8];
  const float* wf   = (const float*)d_in[9];
  const float* bfw  = (const float*)d_in[10];
  const float* wb   = (const float*)d_in[11];
  const float* bbw  = (const float*)d_in[12];
  const float* bn1s = (const float*)d_in[13];
  const float* bn1o = (const float*)d_in[14];
  const float* bn1m = (const float*)d_in[15];
  const float* bn1v = (const float*)d_in[16];
  const float* bn2s = (const float*)d_in[17];
  const float* bn2o = (const float*)d_in[18];
  const float* bn2m = (const float*)d_in[19];
  const float* bn2v = (const float*)d_in[20];
  const float* bn3s = (const float*)d_in[21];
  const float* bn3o = (const float*)d_in[22];
  const float* bn3m = (const float*)d_in[23];
  const float* bn3v = (const float*)d_in[24];
  float* out = (float*)d_out;
  char* ws = (char*)d_ws;

  const size_t ZP   = 0;
  const size_t ACT0 = 8192;
  const size_t ACT1 = ACT0 + 33554432ull;
  const size_t GX0  = ACT1 + 33554432ull;
  const size_t GX1  = GX0 + 134217728ull;
  const size_t HB   = GX1 + 134217728ull;
  const size_t FLG  = HB + 131072ull;

  f16* zp   = (f16*)(ws + ZP);
  f16* act0 = (f16*)(ws + ACT0);
  f16* act1 = (f16*)(ws + ACT1);
  f16* gx0  = (f16*)(ws + GX0);
  f16* gx1  = (f16*)(ws + GX1);
  f16* hb   = (f16*)(ws + HB);
  unsigned* flg = (unsigned*)(ws + FLG);

  (void)hipMemsetAsync(zp, 0, 8192, stream);
  (void)hipMemsetAsync(hb, 0, 131072 + 2048, stream);  // h buffers + flags

  k_embed<<<16384, 256, 0, stream>>>(x, ew, act0);
  k_conv<<<dim3(256, 4), 256, 0, stream>>>(act0, w1, cb1, bn1s, bn1o, bn1m, bn1v, act1, zp);
  k_conv<<<dim3(256, 4), 256, 0, stream>>>(act1, w2, cb2, bn2s, bn2o, bn2m, bn2v, act0, zp);
  k_conv<<<dim3(256, 4), 256, 0, stream>>>(act0, w3, cb3, bn3s, bn3o, bn3m, bn3v, act1, zp);
  k_gx<<<dim3(256, 16), 256, 0, stream>>>(act1, wf, bfw, gx0);
  k_gx<<<dim3(256, 16), 256, 0, stream>>>(act1, wb, bbw, gx1);
  k_lstm<<<32, 256, 0, stream>>>(gx0, gx1, wf, wb, len, hb, flg, out);
}

// Round 2
// 12207.043 us; speedup vs baseline: 1.0523x; 1.0523x over previous
//
#include <hip/hip_runtime.h>
#include <hip/hip_bf16.h>

typedef _Float16 f16;
typedef _Float16 f16x8 __attribute__((ext_vector_type(8)));
typedef _Float16 f16x4 __attribute__((ext_vector_type(4)));
typedef float    f32x4 __attribute__((ext_vector_type(4)));
typedef float    f32x2 __attribute__((ext_vector_type(2)));
typedef unsigned long long u64;

#define DEV static __device__ __forceinline__

// XOR swizzle for [rows][32 f16] (64B-row) LDS tiles: conflict-free b128 frag reads.
DEV int swz(int o) { return o ^ (((o >> 6) & 7) << 4); }

DEV f16x8 u2h8(u64 lo, u64 hi) { union { u64 a[2]; f16x8 b; } c; c.a[0] = lo; c.a[1] = hi; return c.b; }
DEV float sigmf(float x) { return 1.0f / (1.0f + __expf(-x)); }
DEV float tanhf_(float x) { float e = __expf(2.0f * x); return 1.0f - 2.0f / (e + 1.0f); }

// ---------------------------------------------------------------- embed gather
__global__ __launch_bounds__(256) void k_embed(const int* __restrict__ x,
                                               const float* __restrict__ ew,
                                               f16* __restrict__ out) {
  int i = (blockIdx.x * 256 + threadIdx.x) * 4;     // element index into [32768][512]
  int tok = x[i >> 9];
  f32x4 v = *(const f32x4*)(ew + (tok << 9) + (i & 511));
  f16x4 h; h[0] = (f16)v[0]; h[1] = (f16)v[1]; h[2] = (f16)v[2]; h[3] = (f16)v[3];
  *(f16x4*)(out + i) = h;
}

// ------------------------------------------------- conv1d(k=3,SAME)+BN+ReLU
// Implicit GEMM: M=32768 (tiles of 128 rows, batch-aligned), N=512, K=3*512.
__global__ __launch_bounds__(256, 2) void k_conv(
    const f16* __restrict__ in, const float* __restrict__ w,
    const float* __restrict__ bias, const float* __restrict__ bnsc,
    const float* __restrict__ bnof, const float* __restrict__ bnmu,
    const float* __restrict__ bnva, f16* __restrict__ outp,
    const f16* __restrict__ zp) {
  __shared__ f16 Al[4096];   // A tile [128][32] f16, swizzled
  __shared__ f16 Bl[4096];   // B tile transposed [128 cols][32 k] f16, swizzled
  int tid = threadIdx.x, lane = tid & 63, wv = tid >> 6;
  int mb = blockIdx.x, nb = blockIdx.y;
  int wm = (wv >> 1) * 64, wn = (wv & 1) * 64;
  int bb = mb >> 3, l0 = (mb & 7) << 7;      // batch, seq base of tile
  int ar = tid >> 1, ah = tid & 1;           // A staging: row, 32B half
  int bc = (tid & 63) * 2, bkg = tid >> 6;   // B staging: col pair, k-group
  int ko = (lane >> 4) << 4;                 // fragment k byte offset
  f32x4 acc[4][4] = {};
  for (int tap = 0; tap < 3; ++tap) {
    const float* wt = w + tap * 512 * 512 + nb * 128;
    int sl = l0 + ar + tap - 1;              // source seq pos (halo)
    const f16* abase = (sl >= 0 && sl < 1024) ? in + ((bb << 10) + sl) * 512 : nullptr;
    for (int kk = 0; kk < 16; ++kk) {
      const f16* ap = abase ? (abase + kk * 32 + ah * 16) : zp;
      f16x8 a0 = *(const f16x8*)(ap);
      f16x8 a1 = *(const f16x8*)(ap + 8);
      int ao = ar * 64 + ah * 32;
      *(f16x8*)((char*)Al + swz(ao))      = a0;
      *(f16x8*)((char*)Al + swz(ao + 16)) = a1;
      f16x8 b0, b1;
      #pragma unroll
      for (int j = 0; j < 8; ++j) {
        f32x2 f = *(const f32x2*)(wt + (size_t)(kk * 32 + bkg * 8 + j) * 512 + bc);
        b0[j] = (f16)f[0]; b1[j] = (f16)f[1];
      }
      *(f16x8*)((char*)Bl + swz(bc * 64 + bkg * 16))       = b0;
      *(f16x8*)((char*)Bl + swz((bc + 1) * 64 + bkg * 16)) = b1;
      __syncthreads();
      f16x8 af[4], bf[4];
      #pragma unroll
      for (int m = 0; m < 4; ++m)
        af[m] = *(const f16x8*)((char*)Al + swz((wm + m * 16 + (lane & 15)) * 64 + ko));
      #pragma unroll
      for (int n = 0; n < 4; ++n)
        bf[n] = *(const f16x8*)((char*)Bl + swz((wn + n * 16 + (lane & 15)) * 64 + ko));
      #pragma unroll
      for (int m = 0; m < 4; ++m)
        #pragma unroll
        for (int n = 0; n < 4; ++n)
          acc[m][n] = __builtin_amdgcn_mfma_f32_16x16x32_f16(af[m], bf[n], acc[m][n], 0, 0, 0);
      __syncthreads();
    }
  }
  #pragma unroll
  for (int n = 0; n < 4; ++n) {
    int col = nb * 128 + wn + n * 16 + (lane & 15);
    float aa = bnsc[col] / sqrtf(bnva[col] + 1e-5f);
    float bbv = (bias[col] - bnmu[col]) * aa + bnof[col];
    #pragma unroll
    for (int m = 0; m < 4; ++m)
      #pragma unroll
      for (int r = 0; r < 4; ++r) {
        int row = mb * 128 + wm + m * 16 + ((lane >> 4) << 2) + r;
        float v = acc[m][n][r] * aa + bbv;
        outp[(size_t)row * 512 + col] = (f16)fmaxf(v, 0.0f);
      }
  }
}

// --------------------------------- Gx = x @ W[:512] + b  (per direction, fp16 out)
__global__ __launch_bounds__(256, 2) void k_gx(
    const f16* __restrict__ in, const float* __restrict__ W,
    const float* __restrict__ bias, f16* __restrict__ gx) {
  __shared__ f16 Al[4096];
  __shared__ f16 Bl[4096];
  int tid = threadIdx.x, lane = tid & 63, wv = tid >> 6;
  int mb = blockIdx.x, nb = blockIdx.y;   // nb 0..15 (N=2048)
  int wm = (wv >> 1) * 64, wn = (wv & 1) * 64;
  int ar = tid >> 1, ah = tid & 1;
  int bc = (tid & 63) * 2, bkg = tid >> 6;
  int ko = (lane >> 4) << 4;
  f32x4 acc[4][4] = {};
  for (int kk = 0; kk < 16; ++kk) {
    const f16* ap = in + (size_t)(mb * 128 + ar) * 512 + kk * 32 + ah * 16;
    f16x8 a0 = *(const f16x8*)(ap);
    f16x8 a1 = *(const f16x8*)(ap + 8);
    int ao = ar * 64 + ah * 32;
    *(f16x8*)((char*)Al + swz(ao))      = a0;
    *(f16x8*)((char*)Al + swz(ao + 16)) = a1;
    f16x8 b0, b1;
    #pragma unroll
    for (int j = 0; j < 8; ++j) {
      f32x2 f = *(const f32x2*)(W + (size_t)(kk * 32 + bkg * 8 + j) * 2048 + nb * 128 + bc);
      b0[j] = (f16)f[0]; b1[j] = (f16)f[1];
    }
    *(f16x8*)((char*)Bl + swz(bc * 64 + bkg * 16))       = b0;
    *(f16x8*)((char*)Bl + swz((bc + 1) * 64 + bkg * 16)) = b1;
    __syncthreads();
    f16x8 af[4], bf[4];
    #pragma unroll
    for (int m = 0; m < 4; ++m)
      af[m] = *(const f16x8*)((char*)Al + swz((wm + m * 16 + (lane & 15)) * 64 + ko));
    #pragma unroll
    for (int n = 0; n < 4; ++n)
      bf[n] = *(const f16x8*)((char*)Bl + swz((wn + n * 16 + (lane & 15)) * 64 + ko));
    #pragma unroll
    for (int m = 0; m < 4; ++m)
      #pragma unroll
      for (int n = 0; n < 4; ++n)
        acc[m][n] = __builtin_amdgcn_mfma_f32_16x16x32_f16(af[m], bf[n], acc[m][n], 0, 0, 0);
    __syncthreads();
  }
  #pragma unroll
  for (int n = 0; n < 4; ++n) {
    int col = nb * 128 + wn + n * 16 + (lane & 15);
    float bv = bias[col];
    #pragma unroll
    for (int m = 0; m < 4; ++m)
      #pragma unroll
      for (int r = 0; r < 4; ++r) {
        int row = mb * 128 + wm + m * 16 + ((lane >> 4) << 2) + r;
        gx[(size_t)row * 2048 + col] = (f16)(acc[m][n][r] + bv);
      }
  }
}

// ------------------------------------------------------------- BiLSTM recurrence
// 16 persistent WGs: dir = blk>>3, each WG owns 64 hidden units (256 gate cols).
// W_h slice lives in VGPRs as MFMA B-fragments (256 regs/lane).
// Flag-based producer/consumer sync; all cross-WG data via sc1 (agent) atomics,
// so no per-step cache fences are needed: __syncthreads drains vmcnt (release),
// sc1 loads read the LLC coherence point directly (acquire).
__global__ __launch_bounds__(256, 1) void k_lstm(
    const f16* __restrict__ gx0, const f16* __restrict__ gx1,
    const float* __restrict__ Wf, const float* __restrict__ Wb,
    const int* __restrict__ lens,
    f16* __restrict__ hb, unsigned* __restrict__ flg,
    float* __restrict__ outp) {
  __shared__ float gl[32 * 257];  // gates exchange [32 batch][4*64 cols], stride 257
  int wgid = blockIdx.x; int dir = wgid >> 3; int wg = wgid & 7;
  int tid = threadIdx.x, lane = tid & 63, wv = tid >> 6;  // wv = gate (i,g,f,o)
  const float* W = dir ? Wb : Wf;
  const f16* gx = dir ? gx1 : gx0;
  f16* h0 = hb + dir * 32768;                       // 2 buffers of [32][512] f16
  unsigned* myflag = flg + (dir * 8 + wg) * 16;     // 64B-strided flags
  const unsigned* pollp = flg + dir * 128 + (lane & 7) * 16;

  // Preload W_h B-fragments: bfr[nt][kk] covers col wv*512+wg*64+nt*16+(lane&15),
  // rows 512 + kk*32 + (lane>>4)*8 + j.
  f16x8 bfr[4][16];
  {
    int cc0 = wv * 512 + wg * 64 + (lane & 15);
    int r0 = 512 + ((lane >> 4) << 3);
    #pragma unroll
    for (int nt = 0; nt < 4; ++nt)
      #pragma unroll
      for (int kk = 0; kk < 16; ++kk) {
        f16x8 t;
        #pragma unroll
        for (int j = 0; j < 8; ++j)
          t[j] = (f16)W[(size_t)(r0 + kk * 32 + j) * 2048 + cc0 + nt * 16];
        bfr[nt][kk] = t;
      }
  }
  int cb = tid >> 3, u8 = (tid & 7) << 3;   // cell phase: batch, unit base (8 units)
  int lenc = lens[cb];
  int lenr0 = lens[lane & 15];
  int lenr1 = lens[16 + (lane & 15)];
  int kbyte = ((lane >> 4) << 4);
  float c8[8] = {};

  for (int s = 0; s < 1024; ++s) {
    int l = dir ? (1023 - s) : s;
    // Prefetch this step's Gx (independent of h) before polling.
    const f16* gp = gx + ((size_t)((cb << 10) + l)) * 2048 + wg * 64 + u8;
    f16x8 gi8 = *(const f16x8*)(gp);
    f16x8 gg8 = *(const f16x8*)(gp + 512);
    f16x8 gf8 = *(const f16x8*)(gp + 1024);
    f16x8 go8 = *(const f16x8*)(gp + 1536);
    // Wait for all 8 WGs of this direction to have published h_s. (bounded spin)
    for (int spin = 0; spin < (1 << 22); ++spin) {
      unsigned v = __hip_atomic_load(pollp, __ATOMIC_RELAXED, __HIP_MEMORY_SCOPE_AGENT);
      if (__all((int)(v >= (unsigned)s))) break;
      __builtin_amdgcn_s_sleep(1);
    }
    asm volatile("" ::: "memory");   // compiler-only acquire: sc1 loads hit LLC

    const char* hc = (const char*)(h0 + ((s & 1) << 14));
    bool rst0 = dir && (l >= lenr0 - 1);
    bool rst1 = dir && (l >= lenr1 - 1);
    int rb0 = (lane & 15) * 1024 + kbyte;
    int rb1 = rb0 + 16 * 1024;
    f32x4 acc[2][4] = {};
    #pragma unroll
    for (int kk = 0; kk < 16; ++kk) {
      u64 x0 = __hip_atomic_load((const u64*)(hc + rb0 + kk * 64),     __ATOMIC_RELAXED, __HIP_MEMORY_SCOPE_AGENT);
      u64 x1 = __hip_atomic_load((const u64*)(hc + rb0 + kk * 64 + 8), __ATOMIC_RELAXED, __HIP_MEMORY_SCOPE_AGENT);
      u64 y0 = __hip_atomic_load((const u64*)(hc + rb1 + kk * 64),     __ATOMIC_RELAXED, __HIP_MEMORY_SCOPE_AGENT);
      u64 y1 = __hip_atomic_load((const u64*)(hc + rb1 + kk * 64 + 8), __ATOMIC_RELAXED, __HIP_MEMORY_SCOPE_AGENT);
      if (rst0) { x0 = 0; x1 = 0; }
      if (rst1) { y0 = 0; y1 = 0; }
      f16x8 a0 = u2h8(x0, x1), a1 = u2h8(y0, y1);
      #pragma unroll
      for (int nt = 0; nt < 4; ++nt) {
        acc[0][nt] = __builtin_amdgcn_mfma_f32_16x16x32_f16(a0, bfr[nt][kk], acc[0][nt], 0, 0, 0);
        acc[1][nt] = __builtin_amdgcn_mfma_f32_16x16x32_f16(a1, bfr[nt][kk], acc[1][nt], 0, 0, 0);
      }
    }
    int colb = wv * 64 + (lane & 15);
    int rowb = (lane >> 4) << 2;
    #pragma unroll
    for (int nt = 0; nt < 4; ++nt)
      #pragma unroll
      for (int r = 0; r < 4; ++r) {
        gl[(rowb + r) * 257 + colb + nt * 16]      = acc[0][nt][r];
        gl[(rowb + r + 16) * 257 + colb + nt * 16] = acc[1][nt][r];
      }
    __syncthreads();
    bool rstc = dir && (l >= lenc - 1);
    float hv[8];
    #pragma unroll
    for (int q = 0; q < 8; ++q) {
      int u = u8 + q;
      float gi = gl[cb * 257 + u]       + (float)gi8[q];
      float gg = gl[cb * 257 + 64 + u]  + (float)gg8[q];
      float gf = gl[cb * 257 + 128 + u] + (float)gf8[q];
      float go = gl[cb * 257 + 192 + u] + (float)go8[q];
      float cp = rstc ? 0.f : c8[q];
      float it = sigmf(gi);
      float gt = tanhf_(gg);
      float ft = sigmf(gf + 1.0f);
      float ot = sigmf(go);
      float cn = ft * cp + it * gt;
      c8[q] = cn;
      hv[q] = ot * tanhf_(cn);
    }
    union { f16x8 h; u64 u[2]; } hp;
    #pragma unroll
    for (int q = 0; q < 8; ++q) hp.h[q] = (f16)hv[q];
    f16* hdst = h0 + (((s + 1) & 1) << 14) + (cb << 9) + wg * 64 + u8;
    __hip_atomic_store((u64*)hdst,     hp.u[0], __ATOMIC_RELAXED, __HIP_MEMORY_SCOPE_AGENT);
    __hip_atomic_store((u64*)hdst + 1, hp.u[1], __ATOMIC_RELAXED, __HIP_MEMORY_SCOPE_AGENT);
    __syncthreads();   // drains vmcnt(0) per thread -> all h stores LLC-visible
    if (tid == 0)
      __hip_atomic_store(myflag, (unsigned)(s + 1), __ATOMIC_RELEASE, __HIP_MEMORY_SCOPE_AGENT);
    // Output stores AFTER the flag: no in-kernel consumer; they drain during
    // the next step's poll instead of sitting on the serial critical path.
    float* od = outp + ((size_t)((cb << 10) + l) << 10) + (dir << 9) + wg * 64 + u8;
    f32x4 o0, o1;
    o0[0] = hv[0]; o0[1] = hv[1]; o0[2] = hv[2]; o0[3] = hv[3];
    o1[0] = hv[4]; o1[1] = hv[5]; o1[2] = hv[6]; o1[3] = hv[7];
    *(f32x4*)od       = o0;
    *(f32x4*)(od + 4) = o1;
  }
}

// ---------------------------------------------------------------------- launch
extern "C" void kernel_launch(void* const* d_in, const int* in_sizes, int n_in,
                              void* d_out, int out_size, void* d_ws, size_t ws_size,
                              hipStream_t stream) {
  const int*   x    = (const int*)d_in[0];
  const int*   len  = (const int*)d_in[1];
  const float* ew   = (const float*)d_in[2];
  const float* w1   = (const float*)d_in[3];
  const float* cb1  = (const float*)d_in[4];
  const float* w2   = (const float*)d_in[5];
  const float* cb2  = (const float*)d_in[6];
  const float* w3   = (const float*)d_in[7];
  const float* cb3  = (const float*)d_in[8];
  const float* wf   = (const float*)d_in[9];
  const float* bfw  = (const float*)d_in[10];
  const float* wb   = (const float*)d_in[11];
  const float* bbw  = (const float*)d_in[12];
  const float* bn1s = (const float*)d_in[13];
  const float* bn1o = (const float*)d_in[14];
  const float* bn1m = (const float*)d_in[15];
  const float* bn1v = (const float*)d_in[16];
  const float* bn2s = (const float*)d_in[17];
  const float* bn2o = (const float*)d_in[18];
  const float* bn2m = (const float*)d_in[19];
  const float* bn2v = (const float*)d_in[20];
  const float* bn3s = (const float*)d_in[21];
  const float* bn3o = (const float*)d_in[22];
  const float* bn3m = (const float*)d_in[23];
  const float* bn3v = (const float*)d_in[24];
  float* out = (float*)d_out;
  char* ws = (char*)d_ws;

  const size_t ZP   = 0;
  const size_t ACT0 = 8192;
  const size_t ACT1 = ACT0 + 33554432ull;
  const size_t GX0  = ACT1 + 33554432ull;
  const size_t GX1  = GX0 + 134217728ull;
  const size_t HB   = GX1 + 134217728ull;
  const size_t FLG  = HB + 131072ull;

  f16* zp   = (f16*)(ws + ZP);
  f16* act0 = (f16*)(ws + ACT0);
  f16* act1 = (f16*)(ws + ACT1);
  f16* gx0  = (f16*)(ws + GX0);
  f16* gx1  = (f16*)(ws + GX1);
  f16* hb   = (f16*)(ws + HB);
  unsigned* flg = (unsigned*)(ws + FLG);

  (void)hipMemsetAsync(zp, 0, 8192, stream);
  (void)hipMemsetAsync(hb, 0, 131072 + 2048, stream);  // h buffers + flags

  k_embed<<<16384, 256, 0, stream>>>(x, ew, act0);
  k_conv<<<dim3(256, 4), 256, 0, stream>>>(act0, w1, cb1, bn1s, bn1o, bn1m, bn1v, act1, zp);
  k_conv<<<dim3(256, 4), 256, 0, stream>>>(act1, w2, cb2, bn2s, bn2o, bn2m, bn2v, act0, zp);
  k_conv<<<dim3(256, 4), 256, 0, stream>>>(act0, w3, cb3, bn3s, bn3o, bn3m, bn3v, act1, zp);
  k_gx<<<dim3(256, 16), 256, 0, stream>>>(act1, wf, bfw, gx0);
  k_gx<<<dim3(256, 16), 256, 0, stream>>>(act1, wb, bbw, gx1);
  k_lstm<<<16, 256, 0, stream>>>(gx0, gx1, wf, wb, len, hb, flg, out);
}

// Round 4
// 11600.167 us; speedup vs baseline: 1.1074x; 1.0523x over previous
//
#include <hip/hip_runtime.h>
#include <hip/hip_bf16.h>

typedef _Float16 f16;
typedef _Float16 f16x8 __attribute__((ext_vector_type(8)));
typedef _Float16 f16x4 __attribute__((ext_vector_type(4)));
typedef float    f32x4 __attribute__((ext_vector_type(4)));
typedef float    f32x2 __attribute__((ext_vector_type(2)));
typedef unsigned long long u64;

#define DEV static __device__ __forceinline__

// XOR swizzle for [rows][32 f16] (64B-row) LDS tiles: conflict-free b128 frag reads.
DEV int swz(int o) { return o ^ (((o >> 6) & 7) << 4); }

DEV f16x8 u2h8(u64 lo, u64 hi) { union { u64 a[2]; f16x8 b; } c; c.a[0] = lo; c.a[1] = hi; return c.b; }
DEV float sigmf(float x) { return 1.0f / (1.0f + __expf(-x)); }
DEV float tanhf_(float x) { float e = __expf(2.0f * x); return 1.0f - 2.0f / (e + 1.0f); }

// ---------------------------------------------------------------- embed gather
__global__ __launch_bounds__(256) void k_embed(const int* __restrict__ x,
                                               const float* __restrict__ ew,
                                               f16* __restrict__ out) {
  int i = (blockIdx.x * 256 + threadIdx.x) * 4;     // element index into [32768][512]
  int tok = x[i >> 9];
  f32x4 v = *(const f32x4*)(ew + (tok << 9) + (i & 511));
  f16x4 h; h[0] = (f16)v[0]; h[1] = (f16)v[1]; h[2] = (f16)v[2]; h[3] = (f16)v[3];
  *(f16x4*)(out + i) = h;
}

// ------------------------------------------------- conv1d(k=3,SAME)+BN+ReLU
// Implicit GEMM: M=32768 (tiles of 128 rows, batch-aligned), N=512, K=3*512.
__global__ __launch_bounds__(256, 2) void k_conv(
    const f16* __restrict__ in, const float* __restrict__ w,
    const float* __restrict__ bias, const float* __restrict__ bnsc,
    const float* __restrict__ bnof, const float* __restrict__ bnmu,
    const float* __restrict__ bnva, f16* __restrict__ outp,
    const f16* __restrict__ zp) {
  __shared__ f16 Al[4096];   // A tile [128][32] f16, swizzled
  __shared__ f16 Bl[4096];   // B tile transposed [128 cols][32 k] f16, swizzled
  int tid = threadIdx.x, lane = tid & 63, wv = tid >> 6;
  int mb = blockIdx.x, nb = blockIdx.y;
  int wm = (wv >> 1) * 64, wn = (wv & 1) * 64;
  int bb = mb >> 3, l0 = (mb & 7) << 7;      // batch, seq base of tile
  int ar = tid >> 1, ah = tid & 1;           // A staging: row, 32B half
  int bc = (tid & 63) * 2, bkg = tid >> 6;   // B staging: col pair, k-group
  int ko = (lane >> 4) << 4;                 // fragment k byte offset
  f32x4 acc[4][4] = {};
  for (int tap = 0; tap < 3; ++tap) {
    const float* wt = w + tap * 512 * 512 + nb * 128;
    int sl = l0 + ar + tap - 1;              // source seq pos (halo)
    const f16* abase = (sl >= 0 && sl < 1024) ? in + ((bb << 10) + sl) * 512 : nullptr;
    for (int kk = 0; kk < 16; ++kk) {
      const f16* ap = abase ? (abase + kk * 32 + ah * 16) : zp;
      f16x8 a0 = *(const f16x8*)(ap);
      f16x8 a1 = *(const f16x8*)(ap + 8);
      int ao = ar * 64 + ah * 32;
      *(f16x8*)((char*)Al + swz(ao))      = a0;
      *(f16x8*)((char*)Al + swz(ao + 16)) = a1;
      f16x8 b0, b1;
      #pragma unroll
      for (int j = 0; j < 8; ++j) {
        f32x2 f = *(const f32x2*)(wt + (size_t)(kk * 32 + bkg * 8 + j) * 512 + bc);
        b0[j] = (f16)f[0]; b1[j] = (f16)f[1];
      }
      *(f16x8*)((char*)Bl + swz(bc * 64 + bkg * 16))       = b0;
      *(f16x8*)((char*)Bl + swz((bc + 1) * 64 + bkg * 16)) = b1;
      __syncthreads();
      f16x8 af[4], bf[4];
      #pragma unroll
      for (int m = 0; m < 4; ++m)
        af[m] = *(const f16x8*)((char*)Al + swz((wm + m * 16 + (lane & 15)) * 64 + ko));
      #pragma unroll
      for (int n = 0; n < 4; ++n)
        bf[n] = *(const f16x8*)((char*)Bl + swz((wn + n * 16 + (lane & 15)) * 64 + ko));
      #pragma unroll
      for (int m = 0; m < 4; ++m)
        #pragma unroll
        for (int n = 0; n < 4; ++n)
          acc[m][n] = __builtin_amdgcn_mfma_f32_16x16x32_f16(af[m], bf[n], acc[m][n], 0, 0, 0);
      __syncthreads();
    }
  }
  #pragma unroll
  for (int n = 0; n < 4; ++n) {
    int col = nb * 128 + wn + n * 16 + (lane & 15);
    float aa = bnsc[col] / sqrtf(bnva[col] + 1e-5f);
    float bbv = (bias[col] - bnmu[col]) * aa + bnof[col];
    #pragma unroll
    for (int m = 0; m < 4; ++m)
      #pragma unroll
      for (int r = 0; r < 4; ++r) {
        int row = mb * 128 + wm + m * 16 + ((lane >> 4) << 2) + r;
        float v = acc[m][n][r] * aa + bbv;
        outp[(size_t)row * 512 + col] = (f16)fmaxf(v, 0.0f);
      }
  }
}

// --------------------------------- Gx = x @ W[:512] + b  (per direction, fp16 out)
__global__ __launch_bounds__(256, 2) void k_gx(
    const f16* __restrict__ in, const float* __restrict__ W,
    const float* __restrict__ bias, f16* __restrict__ gx) {
  __shared__ f16 Al[4096];
  __shared__ f16 Bl[4096];
  int tid = threadIdx.x, lane = tid & 63, wv = tid >> 6;
  int mb = blockIdx.x, nb = blockIdx.y;   // nb 0..15 (N=2048)
  int wm = (wv >> 1) * 64, wn = (wv & 1) * 64;
  int ar = tid >> 1, ah = tid & 1;
  int bc = (tid & 63) * 2, bkg = tid >> 6;
  int ko = (lane >> 4) << 4;
  f32x4 acc[4][4] = {};
  for (int kk = 0; kk < 16; ++kk) {
    const f16* ap = in + (size_t)(mb * 128 + ar) * 512 + kk * 32 + ah * 16;
    f16x8 a0 = *(const f16x8*)(ap);
    f16x8 a1 = *(const f16x8*)(ap + 8);
    int ao = ar * 64 + ah * 32;
    *(f16x8*)((char*)Al + swz(ao))      = a0;
    *(f16x8*)((char*)Al + swz(ao + 16)) = a1;
    f16x8 b0, b1;
    #pragma unroll
    for (int j = 0; j < 8; ++j) {
      f32x2 f = *(const f32x2*)(W + (size_t)(kk * 32 + bkg * 8 + j) * 2048 + nb * 128 + bc);
      b0[j] = (f16)f[0]; b1[j] = (f16)f[1];
    }
    *(f16x8*)((char*)Bl + swz(bc * 64 + bkg * 16))       = b0;
    *(f16x8*)((char*)Bl + swz((bc + 1) * 64 + bkg * 16)) = b1;
    __syncthreads();
    f16x8 af[4], bf[4];
    #pragma unroll
    for (int m = 0; m < 4; ++m)
      af[m] = *(const f16x8*)((char*)Al + swz((wm + m * 16 + (lane & 15)) * 64 + ko));
    #pragma unroll
    for (int n = 0; n < 4; ++n)
      bf[n] = *(const f16x8*)((char*)Bl + swz((wn + n * 16 + (lane & 15)) * 64 + ko));
    #pragma unroll
    for (int m = 0; m < 4; ++m)
      #pragma unroll
      for (int n = 0; n < 4; ++n)
        acc[m][n] = __builtin_amdgcn_mfma_f32_16x16x32_f16(af[m], bf[n], acc[m][n], 0, 0, 0);
    __syncthreads();
  }
  #pragma unroll
  for (int n = 0; n < 4; ++n) {
    int col = nb * 128 + wn + n * 16 + (lane & 15);
    float bv = bias[col];
    #pragma unroll
    for (int m = 0; m < 4; ++m)
      #pragma unroll
      for (int r = 0; r < 4; ++r) {
        int row = mb * 128 + wm + m * 16 + ((lane >> 4) << 2) + r;
        gx[(size_t)row * 2048 + col] = (f16)(acc[m][n][r] + bv);
      }
  }
}

// ------------------------------------------------------------- BiLSTM recurrence
// 16 persistent WGs: dir = blk>>3, each WG owns 64 hidden units (256 gate cols).
// W_h slice lives in AGPR/VGPR MFMA B-fragments (256 regs/lane).
// Flag-based producer/consumer sync. ALL cross-WG traffic is sc1 (agent-scope
// relaxed atomics) = write-through to / read from the LLC coherence point.
// NO release/acquire fences anywhere in the loop: a release-agent store would
// emit buffer_wbl2 (full 4MB L2 tag-walk writeback, ~10us) on the serial chain
// every step — this was the round-1/2 bottleneck (11us/step invariant).
// Ordering instead: __syncthreads() drains each thread's vmcnt(0), so all h
// sc1-stores are LLC-visible before tid0's RELAXED sc1 flag store issues.
__global__ __launch_bounds__(256, 1) void k_lstm(
    const f16* __restrict__ gx0, const f16* __restrict__ gx1,
    const float* __restrict__ Wf, const float* __restrict__ Wb,
    const int* __restrict__ lens,
    f16* __restrict__ hb, unsigned* __restrict__ flg,
    float* __restrict__ outp) {
  __shared__ float gl[32 * 257];  // gates exchange [32 batch][4*64 cols], stride 257
  int wgid = blockIdx.x; int dir = wgid >> 3; int wg = wgid & 7;
  int tid = threadIdx.x, lane = tid & 63, wv = tid >> 6;  // wv = gate (i,g,f,o)
  const float* W = dir ? Wb : Wf;
  const f16* gx = dir ? gx1 : gx0;
  f16* h0 = hb + dir * 32768;                       // 2 buffers of [32][512] f16
  unsigned* myflag = flg + (dir * 8 + wg) * 16;     // 64B-strided flags
  const unsigned* pollp = flg + dir * 128 + (lane & 7) * 16;

  // Preload W_h B-fragments: bfr[nt][kk] covers col wv*512+wg*64+nt*16+(lane&15),
  // rows 512 + kk*32 + (lane>>4)*8 + j.
  f16x8 bfr[4][16];
  {
    int cc0 = wv * 512 + wg * 64 + (lane & 15);
    int r0 = 512 + ((lane >> 4) << 3);
    #pragma unroll
    for (int nt = 0; nt < 4; ++nt)
      #pragma unroll
      for (int kk = 0; kk < 16; ++kk) {
        f16x8 t;
        #pragma unroll
        for (int j = 0; j < 8; ++j)
          t[j] = (f16)W[(size_t)(r0 + kk * 32 + j) * 2048 + cc0 + nt * 16];
        bfr[nt][kk] = t;
      }
  }
  int cb = tid >> 3, u8 = (tid & 7) << 3;   // cell phase: batch, unit base (8 units)
  int lenc = lens[cb];
  int lenr0 = lens[lane & 15];
  int lenr1 = lens[16 + (lane & 15)];
  int kbyte = ((lane >> 4) << 4);
  float c8[8] = {};

  for (int s = 0; s < 1024; ++s) {
    int l = dir ? (1023 - s) : s;
    // Prefetch this step's Gx (independent of h) before polling.
    const f16* gp = gx + ((size_t)((cb << 10) + l)) * 2048 + wg * 64 + u8;
    f16x8 gi8 = *(const f16x8*)(gp);
    f16x8 gg8 = *(const f16x8*)(gp + 512);
    f16x8 gf8 = *(const f16x8*)(gp + 1024);
    f16x8 go8 = *(const f16x8*)(gp + 1536);
    // Wait for all 8 WGs of this direction to have published h_s. (bounded spin)
    for (int spin = 0; spin < (1 << 22); ++spin) {
      unsigned v = __hip_atomic_load(pollp, __ATOMIC_RELAXED, __HIP_MEMORY_SCOPE_AGENT);
      if (__all((int)(v >= (unsigned)s))) break;
      __builtin_amdgcn_s_sleep(1);
    }
    asm volatile("" ::: "memory");   // compiler-only acquire: sc1 loads hit LLC

    const char* hc = (const char*)(h0 + ((s & 1) << 14));
    bool rst0 = dir && (l >= lenr0 - 1);
    bool rst1 = dir && (l >= lenr1 - 1);
    int rb0 = (lane & 15) * 1024 + kbyte;
    int rb1 = rb0 + 16 * 1024;
    f32x4 acc[2][4] = {};
    #pragma unroll
    for (int kk = 0; kk < 16; ++kk) {
      u64 x0 = __hip_atomic_load((const u64*)(hc + rb0 + kk * 64),     __ATOMIC_RELAXED, __HIP_MEMORY_SCOPE_AGENT);
      u64 x1 = __hip_atomic_load((const u64*)(hc + rb0 + kk * 64 + 8), __ATOMIC_RELAXED, __HIP_MEMORY_SCOPE_AGENT);
      u64 y0 = __hip_atomic_load((const u64*)(hc + rb1 + kk * 64),     __ATOMIC_RELAXED, __HIP_MEMORY_SCOPE_AGENT);
      u64 y1 = __hip_atomic_load((const u64*)(hc + rb1 + kk * 64 + 8), __ATOMIC_RELAXED, __HIP_MEMORY_SCOPE_AGENT);
      if (rst0) { x0 = 0; x1 = 0; }
      if (rst1) { y0 = 0; y1 = 0; }
      f16x8 a0 = u2h8(x0, x1), a1 = u2h8(y0, y1);
      #pragma unroll
      for (int nt = 0; nt < 4; ++nt) {
        acc[0][nt] = __builtin_amdgcn_mfma_f32_16x16x32_f16(a0, bfr[nt][kk], acc[0][nt], 0, 0, 0);
        acc[1][nt] = __builtin_amdgcn_mfma_f32_16x16x32_f16(a1, bfr[nt][kk], acc[1][nt], 0, 0, 0);
      }
    }
    int colb = wv * 64 + (lane & 15);
    int rowb = (lane >> 4) << 2;
    #pragma unroll
    for (int nt = 0; nt < 4; ++nt)
      #pragma unroll
      for (int r = 0; r < 4; ++r) {
        gl[(rowb + r) * 257 + colb + nt * 16]      = acc[0][nt][r];
        gl[(rowb + r + 16) * 257 + colb + nt * 16] = acc[1][nt][r];
      }
    __syncthreads();
    bool rstc = dir && (l >= lenc - 1);
    float hv[8];
    #pragma unroll
    for (int q = 0; q < 8; ++q) {
      int u = u8 + q;
      float gi = gl[cb * 257 + u]       + (float)gi8[q];
      float gg = gl[cb * 257 + 64 + u]  + (float)gg8[q];
      float gf = gl[cb * 257 + 128 + u] + (float)gf8[q];
      float go = gl[cb * 257 + 192 + u] + (float)go8[q];
      float cp = rstc ? 0.f : c8[q];
      float it = sigmf(gi);
      float gt = tanhf_(gg);
      float ft = sigmf(gf + 1.0f);
      float ot = sigmf(go);
      float cn = ft * cp + it * gt;
      c8[q] = cn;
      hv[q] = ot * tanhf_(cn);
    }
    union { f16x8 h; u64 u[2]; } hp;
    #pragma unroll
    for (int q = 0; q < 8; ++q) hp.h[q] = (f16)hv[q];
    f16* hdst = h0 + (((s + 1) & 1) << 14) + (cb << 9) + wg * 64 + u8;
    __hip_atomic_store((u64*)hdst,     hp.u[0], __ATOMIC_RELAXED, __HIP_MEMORY_SCOPE_AGENT);
    __hip_atomic_store((u64*)hdst + 1, hp.u[1], __ATOMIC_RELAXED, __HIP_MEMORY_SCOPE_AGENT);
    __syncthreads();   // drains vmcnt(0) per thread -> all h stores LLC-visible
    if (tid == 0)      // RELAXED: plain sc1 store, no buffer_wbl2 fence
      __hip_atomic_store(myflag, (unsigned)(s + 1), __ATOMIC_RELAXED, __HIP_MEMORY_SCOPE_AGENT);
    // Output stores AFTER the flag: no in-kernel consumer; they drain during
    // the next step's poll instead of sitting on the serial critical path.
    float* od = outp + ((size_t)((cb << 10) + l) << 10) + (dir << 9) + wg * 64 + u8;
    f32x4 o0, o1;
    o0[0] = hv[0]; o0[1] = hv[1]; o0[2] = hv[2]; o0[3] = hv[3];
    o1[0] = hv[4]; o1[1] = hv[5]; o1[2] = hv[6]; o1[3] = hv[7];
    *(f32x4*)od       = o0;
    *(f32x4*)(od + 4) = o1;
  }
}

// ---------------------------------------------------------------------- launch
extern "C" void kernel_launch(void* const* d_in, const int* in_sizes, int n_in,
                              void* d_out, int out_size, void* d_ws, size_t ws_size,
                              hipStream_t stream) {
  const int*   x    = (const int*)d_in[0];
  const int*   len  = (const int*)d_in[1];
  const float* ew   = (const float*)d_in[2];
  const float* w1   = (const float*)d_in[3];
  const float* cb1  = (const float*)d_in[4];
  const float* w2   = (const float*)d_in[5];
  const float* cb2  = (const float*)d_in[6];
  const float* w3   = (const float*)d_in[7];
  const float* cb3  = (const float*)d_in[8];
  const float* wf   = (const float*)d_in[9];
  const float* bfw  = (const float*)d_in[10];
  const float* wb   = (const float*)d_in[11];
  const float* bbw  = (const float*)d_in[12];
  const float* bn1s = (const float*)d_in[13];
  const float* bn1o = (const float*)d_in[14];
  const float* bn1m = (const float*)d_in[15];
  const float* bn1v = (const float*)d_in[16];
  const float* bn2s = (const float*)d_in[17];
  const float* bn2o = (const float*)d_in[18];
  const float* bn2m = (const float*)d_in[19];
  const float* bn2v = (const float*)d_in[20];
  const float* bn3s = (const float*)d_in[21];
  const float* bn3o = (const float*)d_in[22];
  const float* bn3m = (const float*)d_in[23];
  const float* bn3v = (const float*)d_in[24];
  float* out = (float*)d_out;
  char* ws = (char*)d_ws;

  const size_t ZP   = 0;
  const size_t ACT0 = 8192;
  const size_t ACT1 = ACT0 + 33554432ull;
  const size_t GX0  = ACT1 + 33554432ull;
  const size_t GX1  = GX0 + 134217728ull;
  const size_t HB   = GX1 + 134217728ull;
  const size_t FLG  = HB + 131072ull;

  f16* zp   = (f16*)(ws + ZP);
  f16* act0 = (f16*)(ws + ACT0);
  f16* act1 = (f16*)(ws + ACT1);
  f16* gx0  = (f16*)(ws + GX0);
  f16* gx1  = (f16*)(ws + GX1);
  f16* hb   = (f16*)(ws + HB);
  unsigned* flg = (unsigned*)(ws + FLG);

  (void)hipMemsetAsync(zp, 0, 8192, stream);
  (void)hipMemsetAsync(hb, 0, 131072 + 2048, stream);  // h buffers + flags

  k_embed<<<16384, 256, 0, stream>>>(x, ew, act0);
  k_conv<<<dim3(256, 4), 256, 0, stream>>>(act0, w1, cb1, bn1s, bn1o, bn1m, bn1v, act1, zp);
  k_conv<<<dim3(256, 4), 256, 0, stream>>>(act1, w2, cb2, bn2s, bn2o, bn2m, bn2v, act0, zp);
  k_conv<<<dim3(256, 4), 256, 0, stream>>>(act0, w3, cb3, bn3s, bn3o, bn3m, bn3v, act1, zp);
  k_gx<<<dim3(256, 16), 256, 0, stream>>>(act1, wf, bfw, gx0);
  k_gx<<<dim3(256, 16), 256, 0, stream>>>(act1, wb, bbw, gx1);
  k_lstm<<<16, 256, 0, stream>>>(gx0, gx1, wf, wb, len, hb, flg, out);
}

// Round 8
// 6423.282 us; speedup vs baseline: 1.9998x; 1.8060x over previous
//
#include <hip/hip_runtime.h>
#include <hip/hip_bf16.h>

typedef _Float16 f16;
typedef _Float16 f16x8 __attribute__((ext_vector_type(8)));
typedef _Float16 f16x4 __attribute__((ext_vector_type(4)));
typedef float    f32x4 __attribute__((ext_vector_type(4)));
typedef float    f32x2 __attribute__((ext_vector_type(2)));
typedef unsigned long long u64;

#define DEV static __device__ __forceinline__

// XOR swizzle for [rows][32 f16] (64B-row) LDS tiles: conflict-free b128 frag reads.
DEV int swz(int o) { return o ^ (((o >> 6) & 7) << 4); }

DEV f16x8 u2h8(u64 lo, u64 hi) { union { u64 a[2]; f16x8 b; } c; c.a[0] = lo; c.a[1] = hi; return c.b; }
DEV float sigmf(float x) { return 1.0f / (1.0f + __expf(-x)); }
DEV float tanhf_(float x) { float e = __expf(2.0f * x); return 1.0f - 2.0f / (e + 1.0f); }

// ---------------------------------------------------------------- embed gather
__global__ __launch_bounds__(256) void k_embed(const int* __restrict__ x,
                                               const float* __restrict__ ew,
                                               f16* __restrict__ out) {
  int i = (blockIdx.x * 256 + threadIdx.x) * 4;     // element index into [32768][512]
  int tok = x[i >> 9];
  f32x4 v = *(const f32x4*)(ew + (tok << 9) + (i & 511));
  f16x4 h; h[0] = (f16)v[0]; h[1] = (f16)v[1]; h[2] = (f16)v[2]; h[3] = (f16)v[3];
  *(f16x4*)(out + i) = h;
}

// ------------------------------------------------- conv1d(k=3,SAME)+BN+ReLU
// Implicit GEMM: M=32768 (tiles of 128 rows, batch-aligned), N=512, K=3*512.
__global__ __launch_bounds__(256, 2) void k_conv(
    const f16* __restrict__ in, const float* __restrict__ w,
    const float* __restrict__ bias, const float* __restrict__ bnsc,
    const float* __restrict__ bnof, const float* __restrict__ bnmu,
    const float* __restrict__ bnva, f16* __restrict__ outp,
    const f16* __restrict__ zp) {
  __shared__ f16 Al[4096];   // A tile [128][32] f16, swizzled
  __shared__ f16 Bl[4096];   // B tile transposed [128 cols][32 k] f16, swizzled
  int tid = threadIdx.x, lane = tid & 63, wv = tid >> 6;
  int mb = blockIdx.x, nb = blockIdx.y;
  int wm = (wv >> 1) * 64, wn = (wv & 1) * 64;
  int bb = mb >> 3, l0 = (mb & 7) << 7;      // batch, seq base of tile
  int ar = tid >> 1, ah = tid & 1;           // A staging: row, 32B half
  int bc = (tid & 63) * 2, bkg = tid >> 6;   // B staging: col pair, k-group
  int ko = (lane >> 4) << 4;                 // fragment k byte offset
  f32x4 acc[4][4] = {};
  for (int tap = 0; tap < 3; ++tap) {
    const float* wt = w + tap * 512 * 512 + nb * 128;
    int sl = l0 + ar + tap - 1;              // source seq pos (halo)
    const f16* abase = (sl >= 0 && sl < 1024) ? in + ((bb << 10) + sl) * 512 : nullptr;
    for (int kk = 0; kk < 16; ++kk) {
      const f16* ap = abase ? (abase + kk * 32 + ah * 16) : zp;
      f16x8 a0 = *(const f16x8*)(ap);
      f16x8 a1 = *(const f16x8*)(ap + 8);
      int ao = ar * 64 + ah * 32;
      *(f16x8*)((char*)Al + swz(ao))      = a0;
      *(f16x8*)((char*)Al + swz(ao + 16)) = a1;
      f16x8 b0, b1;
      #pragma unroll
      for (int j = 0; j < 8; ++j) {
        f32x2 f = *(const f32x2*)(wt + (size_t)(kk * 32 + bkg * 8 + j) * 512 + bc);
        b0[j] = (f16)f[0]; b1[j] = (f16)f[1];
      }
      *(f16x8*)((char*)Bl + swz(bc * 64 + bkg * 16))       = b0;
      *(f16x8*)((char*)Bl + swz((bc + 1) * 64 + bkg * 16)) = b1;
      __syncthreads();
      f16x8 af[4], bf[4];
      #pragma unroll
      for (int m = 0; m < 4; ++m)
        af[m] = *(const f16x8*)((char*)Al + swz((wm + m * 16 + (lane & 15)) * 64 + ko));
      #pragma unroll
      for (int n = 0; n < 4; ++n)
        bf[n] = *(const f16x8*)((char*)Bl + swz((wn + n * 16 + (lane & 15)) * 64 + ko));
      #pragma unroll
      for (int m = 0; m < 4; ++m)
        #pragma unroll
        for (int n = 0; n < 4; ++n)
          acc[m][n] = __builtin_amdgcn_mfma_f32_16x16x32_f16(af[m], bf[n], acc[m][n], 0, 0, 0);
      __syncthreads();
    }
  }
  #pragma unroll
  for (int n = 0; n < 4; ++n) {
    int col = nb * 128 + wn + n * 16 + (lane & 15);
    float aa = bnsc[col] / sqrtf(bnva[col] + 1e-5f);
    float bbv = (bias[col] - bnmu[col]) * aa + bnof[col];
    #pragma unroll
    for (int m = 0; m < 4; ++m)
      #pragma unroll
      for (int r = 0; r < 4; ++r) {
        int row = mb * 128 + wm + m * 16 + ((lane >> 4) << 2) + r;
        float v = acc[m][n][r] * aa + bbv;
        outp[(size_t)row * 512 + col] = (f16)fmaxf(v, 0.0f);
      }
  }
}

// --------------------------------- Gx = x @ W[:512] + b  (per direction, fp16 out)
__global__ __launch_bounds__(256, 2) void k_gx(
    const f16* __restrict__ in, const float* __restrict__ W,
    const float* __restrict__ bias, f16* __restrict__ gx) {
  __shared__ f16 Al[4096];
  __shared__ f16 Bl[4096];
  int tid = threadIdx.x, lane = tid & 63, wv = tid >> 6;
  int mb = blockIdx.x, nb = blockIdx.y;   // nb 0..15 (N=2048)
  int wm = (wv >> 1) * 64, wn = (wv & 1) * 64;
  int ar = tid >> 1, ah = tid & 1;
  int bc = (tid & 63) * 2, bkg = tid >> 6;
  int ko = (lane >> 4) << 4;
  f32x4 acc[4][4] = {};
  for (int kk = 0; kk < 16; ++kk) {
    const f16* ap = in + (size_t)(mb * 128 + ar) * 512 + kk * 32 + ah * 16;
    f16x8 a0 = *(const f16x8*)(ap);
    f16x8 a1 = *(const f16x8*)(ap + 8);
    int ao = ar * 64 + ah * 32;
    *(f16x8*)((char*)Al + swz(ao))      = a0;
    *(f16x8*)((char*)Al + swz(ao + 16)) = a1;
    f16x8 b0, b1;
    #pragma unroll
    for (int j = 0; j < 8; ++j) {
      f32x2 f = *(const f32x2*)(W + (size_t)(kk * 32 + bkg * 8 + j) * 2048 + nb * 128 + bc);
      b0[j] = (f16)f[0]; b1[j] = (f16)f[1];
    }
    *(f16x8*)((char*)Bl + swz(bc * 64 + bkg * 16))       = b0;
    *(f16x8*)((char*)Bl + swz((bc + 1) * 64 + bkg * 16)) = b1;
    __syncthreads();
    f16x8 af[4], bf[4];
    #pragma unroll
    for (int m = 0; m < 4; ++m)
      af[m] = *(const f16x8*)((char*)Al + swz((wm + m * 16 + (lane & 15)) * 64 + ko));
    #pragma unroll
    for (int n = 0; n < 4; ++n)
      bf[n] = *(const f16x8*)((char*)Bl + swz((wn + n * 16 + (lane & 15)) * 64 + ko));
    #pragma unroll
    for (int m = 0; m < 4; ++m)
      #pragma unroll
      for (int n = 0; n < 4; ++n)
        acc[m][n] = __builtin_amdgcn_mfma_f32_16x16x32_f16(af[m], bf[n], acc[m][n], 0, 0, 0);
    __syncthreads();
  }
  #pragma unroll
  for (int n = 0; n < 4; ++n) {
    int col = nb * 128 + wn + n * 16 + (lane & 15);
    float bv = bias[col];
    #pragma unroll
    for (int m = 0; m < 4; ++m)
      #pragma unroll
      for (int r = 0; r < 4; ++r) {
        int row = mb * 128 + wm + m * 16 + ((lane >> 4) << 2) + r;
        gx[(size_t)row * 2048 + col] = (f16)(acc[m][n][r] + bv);
      }
  }
}

// ------------------------------------------------------------- BiLSTM recurrence
// 16 persistent WGs: dir = blk>>3, each WG owns 64 hidden units (256 gate cols).
// W_h slice in AGPR/VGPR MFMA B-fragments. sc1 (agent) relaxed atomics for all
// cross-WG traffic; no cache-maintenance fences anywhere (round-2/4 lesson).
// Round-5 changes (request-storm reduction ~8x):
//  - h is LDS-staged ONCE per WG (4096 sc1 req/WG/step, was 16384 redundant)
//  - only wave 0 polls flags, with s_sleep(4) backoff (was: all 64 waves
//    hammering 16 hot LLC lines every ~64cy)
//  - length-resets applied during staging (scalar per row), not per-lane
__global__ __launch_bounds__(256, 1) void k_lstm(
    const f16* __restrict__ gx0, const f16* __restrict__ gx1,
    const float* __restrict__ Wf, const float* __restrict__ Wb,
    const int* __restrict__ lens,
    f16* __restrict__ hb, unsigned* __restrict__ flg,
    float* __restrict__ outp) {
  __shared__ f16 hl[32 * 520];    // staged h_s; row stride 520 f16 = 1040 B (bank spread)
  __shared__ float gl[32 * 257];  // gates exchange [32 batch][4*64 cols]
  int wgid = blockIdx.x; int dir = wgid >> 3; int wg = wgid & 7;
  int tid = threadIdx.x, lane = tid & 63, wv = tid >> 6;  // wv = gate (i,g,f,o)
  const float* W = dir ? Wb : Wf;
  const f16* gx = dir ? gx1 : gx0;
  f16* h0 = hb + dir * 32768;                       // 2 buffers of [32][512] f16
  unsigned* myflag = flg + (dir * 8 + wg) * 16;     // 64B-strided flags
  const unsigned* pollp = flg + dir * 128 + (lane & 7) * 16;

  // Preload W_h B-fragments: bfr[nt][kk] covers col wv*512+wg*64+nt*16+(lane&15),
  // rows 512 + kk*32 + (lane>>4)*8 + j.
  f16x8 bfr[4][16];
  {
    int cc0 = wv * 512 + wg * 64 + (lane & 15);
    int r0 = 512 + ((lane >> 4) << 3);
    #pragma unroll
    for (int nt = 0; nt < 4; ++nt)
      #pragma unroll
      for (int kk = 0; kk < 16; ++kk) {
        f16x8 t;
        #pragma unroll
        for (int j = 0; j < 8; ++j)
          t[j] = (f16)W[(size_t)(r0 + kk * 32 + j) * 2048 + cc0 + nt * 16];
        bfr[nt][kk] = t;
      }
  }
  int cb = tid >> 3, u8 = (tid & 7) << 3;   // batch row (staging + cell), unit base
  int lenc = lens[cb];
  float c8[8] = {};

  for (int s = 0; s < 1024; ++s) {
    int l = dir ? (1023 - s) : s;
    // Prefetch this step's Gx (plain cached loads, independent of h).
    const f16* gp = gx + ((size_t)((cb << 10) + l)) * 2048 + wg * 64 + u8;
    f16x8 gi8 = *(const f16x8*)(gp);
    f16x8 gg8 = *(const f16x8*)(gp + 512);
    f16x8 gf8 = *(const f16x8*)(gp + 1024);
    f16x8 go8 = *(const f16x8*)(gp + 1536);

    // Wave 0 polls for all 8 producer WGs of this direction; others wait at B1.
    if (wv == 0) {
      for (int spin = 0; spin < (1 << 20); ++spin) {
        unsigned v = __hip_atomic_load(pollp, __ATOMIC_RELAXED, __HIP_MEMORY_SCOPE_AGENT);
        if (__all((int)(v >= (unsigned)s))) break;
        __builtin_amdgcn_s_sleep(4);
      }
    }
    __syncthreads();   // B1: releases gather

    // Gather h_s -> LDS once per WG. Thread: row cb, 8 chunks of 16B.
    bool rs = dir && (l >= lenc - 1);   // ResetCore: zero h,c where should_reset
    {
      const char* hcb = (const char*)(h0 + ((s & 1) << 14)) + cb * 1024 + (tid & 7) * 16;
      u64 gb[16];
      #pragma unroll
      for (int j = 0; j < 8; ++j) {
        gb[2 * j]     = __hip_atomic_load((const u64*)(hcb + j * 128),     __ATOMIC_RELAXED, __HIP_MEMORY_SCOPE_AGENT);
        gb[2 * j + 1] = __hip_atomic_load((const u64*)(hcb + j * 128 + 8), __ATOMIC_RELAXED, __HIP_MEMORY_SCOPE_AGENT);
      }
      #pragma unroll
      for (int j = 0; j < 8; ++j) {
        u64 a = rs ? 0ull : gb[2 * j], b = rs ? 0ull : gb[2 * j + 1];
        *(f16x8*)(&hl[cb * 520 + ((tid & 7) + 8 * j) * 8]) = u2h8(a, b);
      }
    }
    __syncthreads();   // B2: hl ready

    f32x4 acc[2][4] = {};
    #pragma unroll
    for (int kk = 0; kk < 16; ++kk) {
      f16x8 a0 = *(const f16x8*)(&hl[(lane & 15) * 520 + kk * 32 + (lane >> 4) * 8]);
      f16x8 a1 = *(const f16x8*)(&hl[((lane & 15) + 16) * 520 + kk * 32 + (lane >> 4) * 8]);
      #pragma unroll
      for (int nt = 0; nt < 4; ++nt) {
        acc[0][nt] = __builtin_amdgcn_mfma_f32_16x16x32_f16(a0, bfr[nt][kk], acc[0][nt], 0, 0, 0);
        acc[1][nt] = __builtin_amdgcn_mfma_f32_16x16x32_f16(a1, bfr[nt][kk], acc[1][nt], 0, 0, 0);
      }
    }
    int colb = wv * 64 + (lane & 15);
    int rowb = (lane >> 4) << 2;
    #pragma unroll
    for (int nt = 0; nt < 4; ++nt)
      #pragma unroll
      for (int r = 0; r < 4; ++r) {
        gl[(rowb + r) * 257 + colb + nt * 16]      = acc[0][nt][r];
        gl[(rowb + r + 16) * 257 + colb + nt * 16] = acc[1][nt][r];
      }
    __syncthreads();   // B3: gl ready

    float hv[8];
    #pragma unroll
    for (int q = 0; q < 8; ++q) {
      int u = u8 + q;
      float gi = gl[cb * 257 + u]       + (float)gi8[q];
      float gg = gl[cb * 257 + 64 + u]  + (float)gg8[q];
      float gf = gl[cb * 257 + 128 + u] + (float)gf8[q];
      float go = gl[cb * 257 + 192 + u] + (float)go8[q];
      float cp = rs ? 0.f : c8[q];
      float it = sigmf(gi);
      float gt = tanhf_(gg);
      float ft = sigmf(gf + 1.0f);
      float ot = sigmf(go);
      float cn = ft * cp + it * gt;
      c8[q] = cn;
      hv[q] = ot * tanhf_(cn);
    }
    union { f16x8 h; u64 u[2]; } hp;
    #pragma unroll
    for (int q = 0; q < 8; ++q) hp.h[q] = (f16)hv[q];
    f16* hdst = h0 + (((s + 1) & 1) << 14) + (cb << 9) + wg * 64 + u8;
    __hip_atomic_store((u64*)hdst,     hp.u[0], __ATOMIC_RELAXED, __HIP_MEMORY_SCOPE_AGENT);
    __hip_atomic_store((u64*)hdst + 1, hp.u[1], __ATOMIC_RELAXED, __HIP_MEMORY_SCOPE_AGENT);
    __syncthreads();   // B4: drains vmcnt(0) -> all h stores LLC-visible
    if (tid == 0)      // RELAXED sc1 store, no cache-maintenance fence
      __hip_atomic_store(myflag, (unsigned)(s + 1), __ATOMIC_RELAXED, __HIP_MEMORY_SCOPE_AGENT);
    // Output stores AFTER the flag: drain during the next step's poll.
    float* od = outp + ((size_t)((cb << 10) + l) << 10) + (dir << 9) + wg * 64 + u8;
    f32x4 o0, o1;
    o0[0] = hv[0]; o0[1] = hv[1]; o0[2] = hv[2]; o0[3] = hv[3];
    o1[0] = hv[4]; o1[1] = hv[5]; o1[2] = hv[6]; o1[3] = hv[7];
    *(f32x4*)od       = o0;
    *(f32x4*)(od + 4) = o1;
  }
}

// ---------------------------------------------------------------------- launch
extern "C" void kernel_launch(void* const* d_in, const int* in_sizes, int n_in,
                              void* d_out, int out_size, void* d_ws, size_t ws_size,
                              hipStream_t stream) {
  const int*   x    = (const int*)d_in[0];
  const int*   len  = (const int*)d_in[1];
  const float* ew   = (const float*)d_in[2];
  const float* w1   = (const float*)d_in[3];
  const float* cb1  = (const float*)d_in[4];
  const float* w2   = (const float*)d_in[5];
  const float* cb2  = (const float*)d_in[6];
  const float* w3   = (const float*)d_in[7];
  const float* cb3  = (const float*)d_in[8];
  const float* wf   = (const float*)d_in[9];
  const float* bfw  = (const float*)d_in[10];
  const float* wb   = (const float*)d_in[11];
  const float* bbw  = (const float*)d_in[12];
  const float* bn1s = (const float*)d_in[13];
  const float* bn1o = (const float*)d_in[14];
  const float* bn1m = (const float*)d_in[15];
  const float* bn1v = (const float*)d_in[16];
  const float* bn2s = (const float*)d_in[17];
  const float* bn2o = (const float*)d_in[18];
  const float* bn2m = (const float*)d_in[19];
  const float* bn2v = (const float*)d_in[20];
  const float* bn3s = (const float*)d_in[21];
  const float* bn3o = (const float*)d_in[22];
  const float* bn3m = (const float*)d_in[23];
  const float* bn3v = (const float*)d_in[24];
  float* out = (float*)d_out;
  char* ws = (char*)d_ws;

  const size_t ZP   = 0;
  const size_t ACT0 = 8192;
  const size_t ACT1 = ACT0 + 33554432ull;
  const size_t GX0  = ACT1 + 33554432ull;
  const size_t GX1  = GX0 + 134217728ull;
  const size_t HB   = GX1 + 134217728ull;
  const size_t FLG  = HB + 131072ull;

  f16* zp   = (f16*)(ws + ZP);
  f16* act0 = (f16*)(ws + ACT0);
  f16* act1 = (f16*)(ws + ACT1);
  f16* gx0  = (f16*)(ws + GX0);
  f16* gx1  = (f16*)(ws + GX1);
  f16* hb   = (f16*)(ws + HB);
  unsigned* flg = (unsigned*)(ws + FLG);

  (void)hipMemsetAsync(zp, 0, 8192, stream);
  (void)hipMemsetAsync(hb, 0, 131072 + 2048, stream);  // h buffers + flags

  k_embed<<<16384, 256, 0, stream>>>(x, ew, act0);
  k_conv<<<dim3(256, 4), 256, 0, stream>>>(act0, w1, cb1, bn1s, bn1o, bn1m, bn1v, act1, zp);
  k_conv<<<dim3(256, 4), 256, 0, stream>>>(act1, w2, cb2, bn2s, bn2o, bn2m, bn2v, act0, zp);
  k_conv<<<dim3(256, 4), 256, 0, stream>>>(act0, w3, cb3, bn3s, bn3o, bn3m, bn3v, act1, zp);
  k_gx<<<dim3(256, 16), 256, 0, stream>>>(act1, wf, bfw, gx0);
  k_gx<<<dim3(256, 16), 256, 0, stream>>>(act1, wb, bbw, gx1);
  k_lstm<<<16, 256, 0, stream>>>(gx0, gx1, wf, wb, len, hb, flg, out);
}